// Round 6
// baseline (173.699 us; speedup 1.0000x reference)
//
#include <hip/hip_runtime.h>

using bf16   = __bf16;
using bf16x4 = __bf16 __attribute__((ext_vector_type(4)));
using bf16x8 = __bf16 __attribute__((ext_vector_type(8)));
using f32x4  = float __attribute__((ext_vector_type(4)));
using f32x16 = float __attribute__((ext_vector_type(16)));
using u32x2  = unsigned int __attribute__((ext_vector_type(2)));
using u32x4  = unsigned int __attribute__((ext_vector_type(4)));

#define L_SEQ  2048
#define DMODEL 2048
#define NQH    32
#define NKVH   8
#define HDIM   64
#define QKV_N  3072   // NQH*HDIM + 2*NKVH*HDIM

// fragment-ordered K/V: per kv-head, 64 key-blocks of 32; each block = 4 frags
// of (64 lanes x 8 elems) = 2048 elems; per-head stride:
#define KVF_HSTRIDE (64 * 4 * 64 * 8)   // 131072 elems = 256 KiB

// ---------- helpers ----------
__device__ __forceinline__ void gload_lds16(const void* g, void* lds) {
  __builtin_amdgcn_global_load_lds((__attribute__((address_space(1))) void*)(g),
                                   (__attribute__((address_space(3))) void*)(lds),
                                   16, 0, 0);
}

__device__ __forceinline__ unsigned pack2(float a, float b) {
  union { bf16 h[2]; unsigned u; } x;
  x.h[0] = (bf16)a; x.h[1] = (bf16)b;
  return x.u;
}

// ---------- fp32 -> bf16 convert ----------
__global__ void cvt_f32_bf16(const float* __restrict__ in, bf16* __restrict__ out, long n) {
  const long stride = (long)gridDim.x * blockDim.x;
  const long n4 = n >> 2;
  for (long i = (long)blockIdx.x * blockDim.x + threadIdx.x; i < n4; i += stride) {
    const float4 v = reinterpret_cast<const float4*>(in)[i];
    bf16x4 o = { (bf16)v.x, (bf16)v.y, (bf16)v.z, (bf16)v.w };
    reinterpret_cast<bf16x4*>(out)[i] = o;
  }
}

// ---------- bf16 GEMM: C(MxN) = A(MxK) * B(NxK)^T, 128x64 tile, BK=64 ----------
// 2 waves per block; each wave computes the FULL 64x64 half-tile.
template <typename OutT>
__global__ __launch_bounds__(128)
void gemm_bt(const bf16* __restrict__ A, const bf16* __restrict__ B,
             OutT* __restrict__ C, int M, int N, int K) {
  __shared__ bf16 As[128 * 64];
  __shared__ bf16 Bs[64 * 64];
  const int tid = threadIdx.x;
  const int w = tid >> 6, l = tid & 63;
  const int lq = l & 15, lg = l >> 4;
  const long m0 = (long)blockIdx.y * 128;
  const long n0 = (long)blockIdx.x * 64;

  const int lrow = l >> 3;                   // row within 8-row group (0..7)
  const int scol = ((l & 7) ^ lrow) << 3;    // pre-swizzled global element column

  f32x4 acc[4][4];
#pragma unroll
  for (int i = 0; i < 4; ++i)
#pragma unroll
    for (int j = 0; j < 4; ++j) acc[i][j] = f32x4{0.f, 0.f, 0.f, 0.f};

  for (int k0 = 0; k0 < K; k0 += 64) {
#pragma unroll
    for (int i = 0; i < 8; ++i) {
      const int r0 = (i * 2 + w) * 8;
      gload_lds16(A + (m0 + r0 + lrow) * (long)K + k0 + scol, &As[r0 * 64]);
    }
#pragma unroll
    for (int i = 0; i < 4; ++i) {
      const int r0 = (i * 2 + w) * 8;
      gload_lds16(B + (n0 + r0 + lrow) * (long)K + k0 + scol, &Bs[r0 * 64]);
    }
    __syncthreads();
#pragma unroll
    for (int kk = 0; kk < 2; ++kk) {
      bf16x8 af[4], bfr[4];
#pragma unroll
      for (int t = 0; t < 4; ++t) {
        const int rowA = w * 64 + t * 16 + lq;
        const int blkA = (kk * 4 + lg) ^ (rowA & 7);
        af[t] = *reinterpret_cast<const bf16x8*>(&As[rowA * 64 + blkA * 8]);
        const int rowB = t * 16 + lq;
        const int blkB = (kk * 4 + lg) ^ (rowB & 7);
        bfr[t] = *reinterpret_cast<const bf16x8*>(&Bs[rowB * 64 + blkB * 8]);
      }
#pragma unroll
      for (int mt = 0; mt < 4; ++mt)
#pragma unroll
        for (int nt = 0; nt < 4; ++nt)
          acc[mt][nt] = __builtin_amdgcn_mfma_f32_16x16x32_bf16(af[mt], bfr[nt], acc[mt][nt], 0, 0, 0);
    }
    __syncthreads();
  }

#pragma unroll
  for (int mt = 0; mt < 4; ++mt)
#pragma unroll
    for (int r = 0; r < 4; ++r) {
      const long row = m0 + w * 64 + mt * 16 + lg * 4 + r;
#pragma unroll
      for (int nt = 0; nt < 4; ++nt) {
        const long col = n0 + nt * 16 + lq;
        C[row * (long)N + col] = (OutT)acc[mt][nt][r];
      }
    }
}

// ---------- RoPE + RMSNorm for Q and K ----------
// Q scaled by SCALE*log2(e); K written directly in MFMA-fragment order.
__global__ __launch_bounds__(256)
void rope_rms(const bf16* __restrict__ qkv, const float* __restrict__ qg,
              const float* __restrict__ kg, bf16* __restrict__ qo, bf16* __restrict__ kfr) {
  const int gid = blockIdx.x * 4 + (threadIdx.x >> 6);
  const int lane = threadIdx.x & 63;
  const int pos = gid / 40;
  const int hh = gid % 40;            // 0..31 q heads, 32..39 k heads
  const bool isq = hh < 32;
  const int col = isq ? hh * HDIM : NQH * HDIM + (hh - 32) * HDIM;

  float x = (float)qkv[(long)pos * QKV_N + col + lane];
  float p = __shfl_xor(x, 1);
  const float fi = (float)(lane & ~1) * (1.0f / 64.0f);
  const float inv = powf(50000.0f, -fi);
  const float ang = (float)pos * inv;
  const float sn = sinf(ang), cs = cosf(ang);
  const float r = (lane & 1) ? (p * sn + x * cs) : (x * cs - p * sn);

  float ss = r * r;
#pragma unroll
  for (int off = 1; off < 64; off <<= 1) ss += __shfl_xor(ss, off);
  const float scl = rsqrtf(ss * (1.0f / 64.0f) + 1e-5f);
  const float g = isq ? qg[lane] : kg[lane];
  const float o = r * scl * g;

  if (isq) {
    qo[(long)pos * DMODEL + hh * HDIM + lane] = (bf16)(o * 0.18033688011112042f);
  } else {
    const int kvh = hh - 32;
    const int d = lane;
    const int lp = (pos & 31) + (((d >> 3) & 1) << 5);
    const long idx = ((((long)kvh * 64 + (pos >> 5)) * 4 + (d >> 4)) * 64 + lp) * 8 + (d & 7);
    kfr[idx] = (bf16)o;
  }
}

// ---------- V repack: qkv cols [2560,3072) -> vfr in MFMA-fragment order ----------
__global__ __launch_bounds__(256)
void repack_v(const bf16* __restrict__ qkv, bf16* __restrict__ vfr) {
  __shared__ bf16 t[32][72];
  const int kvh = blockIdx.x >> 6;
  const int kb = blockIdx.x & 63;
  const int tid = threadIdx.x;

  {
    const int row = tid >> 3;
    const int cc = (tid & 7) * 8;
    const bf16* g = qkv + (long)(kb * 32 + row) * QKV_N + (NQH * HDIM + NKVH * HDIM) + kvh * HDIM + cc;
    *reinterpret_cast<u32x4*>(&t[row][cc]) = *reinterpret_cast<const u32x4*>(g);
  }
  __syncthreads();

  const int f = tid >> 6, l = tid & 63;
  const int s = f >> 1, dh = f & 1;
  const int hi = l >> 5, l31 = l & 31;
  union { bf16 b[8]; u32x4 u; } o;
#pragma unroll
  for (int e = 0; e < 8; ++e) o.b[e] = t[s * 16 + hi * 8 + e][dh * 32 + l31];
  bf16* od = vfr + (((long)(kvh * 64 + kb) * 4 + f) * 64 + l) * 8;
  *reinterpret_cast<u32x4*>(od) = o.u;
}

// ---------- flash attention (causal, GQA), split-K, balanced schedule ----------
// 3072 work units (3 waves/SIMD): tiles qi>=32 split into two key-range halves
// (partials -> po/pm/pl, merged by combine_split); qi<32 finalize in-kernel.
// Block classes: A (bb<512): 4 complementary split-units, ~equal block work.
//                B (bb>=512): 4 complementary unsplit units.
__global__ __launch_bounds__(256)
void flash_attn(const bf16* __restrict__ Q, const bf16* __restrict__ Kfr,
                const bf16* __restrict__ Vfr, bf16* __restrict__ Og,
                float* __restrict__ po, float* __restrict__ pm, float* __restrict__ pl) {
  const int w = threadIdx.x >> 6, l = threadIdx.x & 63;
  const int lane31 = l & 31, hi = l >> 5;
  const int bb = blockIdx.x;

  int h, qi, s0, s1, part;
  bool split;
  if (bb < 512) {                       // A-class: split halves of qi in [32,64)
    h = bb & 31;
    const int a = bb >> 5;              // 0..15
    const int xs[4] = { a, 31 - a, 32 + a, 63 - a };
    const int x = xs[w];                // 0..63, sizes descending in x
    qi = 63 - (x >> 1);
    part = x & 1;
    const int nst = qi + 1, h1 = (nst + 1) >> 1;
    s0 = part ? h1 : 0;
    s1 = part ? nst : h1;
    split = true;
  } else {                              // B-class: unsplit qi in [0,32)
    const int u = bb - 512;
    h = u & 31;
    const int b = u >> 5;               // 0..7
    const int ys[4] = { b, 15 - b, 16 + b, 31 - b };
    qi = 31 - ys[w];
    s0 = 0; s1 = qi + 1; part = 0;
    split = false;
  }

  const int kvh = h >> 2;
  const int q0 = qi * 32;
  const int q_abs = q0 + lane31;
  const int l8 = l * 8;

  // Q fragments (B-frag of ST): lane -> Q[q0+lane31][c*16 + hi*8 + e]
  const bf16* qrow = Q + (long)q_abs * DMODEL + h * HDIM + hi * 8;
  bf16x8 qf[4];
#pragma unroll
  for (int c = 0; c < 4; ++c) qf[c] = *reinterpret_cast<const bf16x8*>(qrow + c * 16);

  f32x16 o0, o1;
#pragma unroll
  for (int r = 0; r < 16; ++r) { o0[r] = 0.f; o1[r] = 0.f; }
  float m = -3.0e38f, lsum = 0.f;

  const bf16* kfrh = Kfr + (long)kvh * KVF_HSTRIDE;
  const bf16* vfrh = Vfr + (long)kvh * KVF_HSTRIDE;

  // prologue: K fragments for first subtile
  bf16x8 kc0, kc1, kc2, kc3;
  {
    const bf16* kp = kfrh + (long)s0 * 2048 + l8;
    kc0 = *reinterpret_cast<const bf16x8*>(kp);
    kc1 = *reinterpret_cast<const bf16x8*>(kp + 512);
    kc2 = *reinterpret_cast<const bf16x8*>(kp + 1024);
    kc3 = *reinterpret_cast<const bf16x8*>(kp + 1536);
  }

  for (int sti = s0; sti < s1; ++sti) {
    const int kb0 = sti * 32;

    // V loads for THIS iter issued early (consumed after softmax)
    const bf16* vp = vfrh + (long)sti * 2048 + l8;
    const bf16x8 va0 = *reinterpret_cast<const bf16x8*>(vp);
    const bf16x8 vb0 = *reinterpret_cast<const bf16x8*>(vp + 512);
    const bf16x8 va1 = *reinterpret_cast<const bf16x8*>(vp + 1024);
    const bf16x8 vb1 = *reinterpret_cast<const bf16x8*>(vp + 1536);

    // NEXT iter's K loads (clamped, branchless)
    const long knoff = (sti + 1 < s1) ? (long)(sti + 1) * 2048 : (long)s0 * 2048;
    const bf16* kp = kfrh + knoff + l8;
    const bf16x8 kn0 = *reinterpret_cast<const bf16x8*>(kp);
    const bf16x8 kn1 = *reinterpret_cast<const bf16x8*>(kp + 512);
    const bf16x8 kn2 = *reinterpret_cast<const bf16x8*>(kp + 1024);
    const bf16x8 kn3 = *reinterpret_cast<const bf16x8*>(kp + 1536);

    // ---- ST = K * Q^T over 4 d-chunks ----
    f32x16 st;
#pragma unroll
    for (int r = 0; r < 16; ++r) st[r] = 0.f;
    st = __builtin_amdgcn_mfma_f32_32x32x16_bf16(kc0, qf[0], st, 0, 0, 0);
    st = __builtin_amdgcn_mfma_f32_32x32x16_bf16(kc1, qf[1], st, 0, 0, 0);
    st = __builtin_amdgcn_mfma_f32_32x32x16_bf16(kc2, qf[2], st, 0, 0, 0);
    st = __builtin_amdgcn_mfma_f32_32x32x16_bf16(kc3, qf[3], st, 0, 0, 0);

    // ---- causal mask (diagonal tile only) ----
    if (kb0 + 31 > q0) {
#pragma unroll
      for (int r = 0; r < 16; ++r) {
        const int k_abs = kb0 + (r & 3) + 8 * (r >> 2) + 4 * hi;
        if (k_abs > q_abs) st[r] = -3.0e38f;
      }
    }

    // ---- online softmax (base-2 domain; scale folded into Q) ----
    float mx = st[0];
#pragma unroll
    for (int r = 1; r < 16; ++r) mx = fmaxf(mx, st[r]);
    mx = fmaxf(mx, __shfl_xor(mx, 32));
    if (!__all(mx - m <= 8.0f)) {        // defer-max, THR=8
      const float mn = fmaxf(m, mx);
      const float al = __builtin_amdgcn_exp2f(m - mn);
      m = mn; lsum *= al;
#pragma unroll
      for (int r = 0; r < 16; ++r) { o0[r] *= al; o1[r] *= al; }
    }
    float p[16];
    float rs = 0.f;
#pragma unroll
    for (int r = 0; r < 16; ++r) { p[r] = __builtin_amdgcn_exp2f(st[r] - m); rs += p[r]; }
    rs += __shfl_xor(rs, 32);
    lsum += rs;

    // ---- PV: assemble P B-frags in-register, 2 k-slices ----
#pragma unroll
    for (int s = 0; s < 2; ++s) {
      const int j = s * 8;
      const unsigned W0 = pack2(p[j + 0], p[j + 1]);
      const unsigned W1 = pack2(p[j + 2], p[j + 3]);
      const unsigned W2 = pack2(p[j + 4], p[j + 5]);
      const unsigned W3 = pack2(p[j + 6], p[j + 7]);
      u32x4 pw;
#if __has_builtin(__builtin_amdgcn_permlane32_swap)
      {
        using i32x2 = int __attribute__((ext_vector_type(2)));
        const i32x2 r02 = __builtin_amdgcn_permlane32_swap((int)W0, (int)W2, false, false);
        const i32x2 r13 = __builtin_amdgcn_permlane32_swap((int)W1, (int)W3, false, false);
        pw = u32x4{ (unsigned)r02[0], (unsigned)r13[0], (unsigned)r02[1], (unsigned)r13[1] };
      }
#else
      {
        const unsigned X0 = (unsigned)__shfl_xor((int)W0, 32);
        const unsigned X1 = (unsigned)__shfl_xor((int)W1, 32);
        const unsigned X2 = (unsigned)__shfl_xor((int)W2, 32);
        const unsigned X3 = (unsigned)__shfl_xor((int)W3, 32);
        pw = u32x4{ hi ? X2 : W0, hi ? X3 : W1, hi ? W2 : X0, hi ? W3 : X1 };
      }
#endif
      const bf16x8 pf = __builtin_bit_cast(bf16x8, pw);
      if (s == 0) {
        o0 = __builtin_amdgcn_mfma_f32_32x32x16_bf16(va0, pf, o0, 0, 0, 0);
        o1 = __builtin_amdgcn_mfma_f32_32x32x16_bf16(vb0, pf, o1, 0, 0, 0);
      } else {
        o0 = __builtin_amdgcn_mfma_f32_32x32x16_bf16(va1, pf, o0, 0, 0, 0);
        o1 = __builtin_amdgcn_mfma_f32_32x32x16_bf16(vb1, pf, o1, 0, 0, 0);
      }
    }

    kc0 = kn0; kc1 = kn1; kc2 = kn2; kc3 = kn3;
  }

  if (split) {
    // ---- store raw partials (f32) + stats ----
    const int pidx = (h * 32 + (qi - 32)) * 2 + part;
    float* pbase = po + (long)pidx * 2048 + lane31 * 64;
#pragma unroll
    for (int g = 0; g < 4; ++g) {
      const int d0 = 8 * g + 4 * hi;
      *reinterpret_cast<f32x4*>(pbase + d0) =
          f32x4{ o0[4 * g + 0], o0[4 * g + 1], o0[4 * g + 2], o0[4 * g + 3] };
      *reinterpret_cast<f32x4*>(pbase + 32 + d0) =
          f32x4{ o1[4 * g + 0], o1[4 * g + 1], o1[4 * g + 2], o1[4 * g + 3] };
    }
    if (hi == 0) {
      pm[pidx * 32 + lane31] = m;
      pl[pidx * 32 + lane31] = lsum;
    }
  } else {
    // ---- normalize + store: lane owns q-row, regs span d ----
    const float rl = 1.0f / lsum;
    bf16* orow = Og + (long)q_abs * DMODEL + h * HDIM;
#pragma unroll
    for (int g = 0; g < 4; ++g) {
      const int d0 = 8 * g + 4 * hi;
      u32x2 s0v = { pack2(o0[4 * g + 0] * rl, o0[4 * g + 1] * rl),
                    pack2(o0[4 * g + 2] * rl, o0[4 * g + 3] * rl) };
      u32x2 s1v = { pack2(o1[4 * g + 0] * rl, o1[4 * g + 1] * rl),
                    pack2(o1[4 * g + 2] * rl, o1[4 * g + 3] * rl) };
      *reinterpret_cast<u32x2*>(orow + d0) = s0v;
      *reinterpret_cast<u32x2*>(orow + 32 + d0) = s1v;
    }
  }
}

// ---------- combine split partials: ao[q] = (oa*ea + ob*eb) / (la*ea + lb*eb) ----------
// 1024 split tiles (h, qi in [32,64)); 128 threads per tile: (q-row, 16-d chunk).
__global__ __launch_bounds__(256)
void combine_split(const float* __restrict__ po, const float* __restrict__ pm,
                   const float* __restrict__ pl, bf16* __restrict__ ao) {
  const int t = blockIdx.x * 2 + (threadIdx.x >> 7);
  const int tid7 = threadIdx.x & 127;
  const int r = tid7 >> 2;
  const int dc = (tid7 & 3) * 16;
  const int h = t >> 5, qi32 = t & 31;
  const int pA = t * 2, pB = pA + 1;

  const float ma = pm[pA * 32 + r], mb = pm[pB * 32 + r];
  const float la = pl[pA * 32 + r], lb = pl[pB * 32 + r];
  const float M = fmaxf(ma, mb);
  const float ea = __builtin_amdgcn_exp2f(ma - M);
  const float eb = __builtin_amdgcn_exp2f(mb - M);
  const float inv = 1.0f / (la * ea + lb * eb);
  const float fa = ea * inv, fb = eb * inv;

  const float* oa = po + (long)pA * 2048 + r * 64 + dc;
  const float* ob = po + (long)pB * 2048 + r * 64 + dc;
  const long q_abs = (long)(qi32 + 32) * 32 + r;
  bf16* od = ao + q_abs * DMODEL + h * HDIM + dc;

  union { bf16 b[16]; u32x4 u[2]; } o;
#pragma unroll
  for (int j = 0; j < 4; ++j) {
    const float4 a = reinterpret_cast<const float4*>(oa)[j];
    const float4 b = reinterpret_cast<const float4*>(ob)[j];
    o.b[4 * j + 0] = (bf16)(a.x * fa + b.x * fb);
    o.b[4 * j + 1] = (bf16)(a.y * fa + b.y * fb);
    o.b[4 * j + 2] = (bf16)(a.z * fa + b.z * fb);
    o.b[4 * j + 3] = (bf16)(a.w * fa + b.w * fb);
  }
  *reinterpret_cast<u32x4*>(od) = o.u[0];
  *reinterpret_cast<u32x4*>(od + 8) = o.u[1];
}

// ---------- launch ----------
extern "C" void kernel_launch(void* const* d_in, const int* in_sizes, int n_in,
                              void* d_out, int out_size, void* d_ws, size_t ws_size,
                              hipStream_t stream) {
  const float* x       = (const float*)d_in[0];
  const float* w_qkv   = (const float*)d_in[1];
  const float* w_out   = (const float*)d_in[2];
  const float* q_gamma = (const float*)d_in[3];
  const float* k_gamma = (const float*)d_in[4];
  // d_in[5] = mask (causal tril) — implemented analytically.

  char* ws = (char*)d_ws;
  bf16* xb  = (bf16*)(ws);                       //  8 MiB  x bf16 (dead after gemm1)
  bf16* wqb = (bf16*)(ws + (8ul  << 20));        // 12 MiB  w_qkv bf16 (dead after gemm1)
  bf16* wob = (bf16*)(ws + (20ul << 20));        //  8 MiB  w_out bf16
  bf16* qkv = (bf16*)(ws + (28ul << 20));        // 12 MiB  qkv bf16
  bf16* qb  = (bf16*)(ws + (40ul << 20));        //  8 MiB  roped/normed Q (pre-scaled)
  bf16* kfr = (bf16*)(ws + (48ul << 20));        //  2 MiB  roped/normed K, frag order
  bf16* vfr = (bf16*)(ws + (50ul << 20));        //  2 MiB  V, frag order
  bf16* ao  = (bf16*)(ws + (52ul << 20));        //  8 MiB  attention out
  // split-K partials overlay xb/wqb (both dead once flash_attn runs):
  float* po = (float*)(ws);                      // 16 MiB  partial O (2048 units x 8KB)
  float* pm = (float*)(ws + (16ul << 20));       // 256 KiB partial max
  float* pl = (float*)(ws + (16ul << 20) + (1ul << 18)); // 256 KiB partial lsum
  float* out = (float*)d_out;

  cvt_f32_bf16<<<2048, 256, 0, stream>>>(x, xb, (long)L_SEQ * DMODEL);
  cvt_f32_bf16<<<2048, 256, 0, stream>>>(w_qkv, wqb, (long)QKV_N * DMODEL);
  cvt_f32_bf16<<<2048, 256, 0, stream>>>(w_out, wob, (long)DMODEL * DMODEL);

  gemm_bt<bf16><<<dim3(QKV_N / 64, L_SEQ / 128), 128, 0, stream>>>(xb, wqb, qkv, L_SEQ, QKV_N, DMODEL);

  rope_rms<<<(L_SEQ * 40) / 4, 256, 0, stream>>>(qkv, q_gamma, k_gamma, qb, kfr);
  repack_v<<<NKVH * (L_SEQ / 32), 256, 0, stream>>>(qkv, vfr);

  flash_attn<<<768, 256, 0, stream>>>(qb, kfr, vfr, ao, po, pm, pl);
  combine_split<<<512, 256, 0, stream>>>(po, pm, pl, ao);

  gemm_bt<float><<<dim3(DMODEL / 64, L_SEQ / 128), 128, 0, stream>>>(ao, wob, out, L_SEQ, DMODEL, DMODEL);
}